// Round 3
// baseline (11250.548 us; speedup 1.0000x reference)
//
#include <hip/hip_runtime.h>
#include <hip/hip_bf16.h>

#define NPTS 8192
#define SDIM 5
#define NBATCH 4
#define NS 4096
#define FEAT 64
#define KNN 3

// ws layout
#define WS_SIDX_OFF   0               // 4*4096*4   = 64 KB
#define WS_KNN_OFF    65536           // 4*4096*3*4 = 192 KB
#define WS_WT_OFF     262144          // 7*4096*4   = 112 KB
#define WS_SLOTS_OFF  524288          // 4*4096*16*8 = 2 MB
#define WS_SLOTS_BYTES ((size_t)NBATCH * NS * 16 * 8)
#define WS_NEED       (WS_SLOTS_OFF + WS_SLOTS_BYTES)

// Pin a value to a VGPR so the compiler cannot contract mul+add into FMA
// (must match numpy's separate-mul-then-add f32 rounding for argmax/top-k
// index stability).
#define NOFUSE(x) asm volatile("" : "+v"(x))

__device__ __forceinline__ float sqdist5(float p0, float p1, float p2, float p3, float p4,
                                         float q0, float q1, float q2, float q3, float q4)
{
    float d0 = p0 - q0, d1 = p1 - q1, d2 = p2 - q2, d3 = p3 - q3, d4 = p4 - q4;
    float m0 = d0 * d0; NOFUSE(m0);
    float m1 = d1 * d1; NOFUSE(m1);
    float m2 = d2 * d2; NOFUSE(m2);
    float m3 = d3 * d3; NOFUSE(m3);
    float m4 = d4 * d4; NOFUSE(m4);
    float a = m0 + m1;  // numpy sum order for n=5: sequential left-assoc
    a = a + m2;
    a = a + m3;
    a = a + m4;
    return a;
}

// ---------------------------------------------------------------------------
// Kernel 1 (v2): multi-CU farthest point sampling, zero barriers.
// 4 blocks/batch x 256 threads (4 waves). Wave wv (0..15) owns points
// [wv*512, wv*512+512), 8 per lane. Per step each wave publishes its shard
// argmax as a self-contained u64 key into slots[b][step][wv] (agent atomic),
// polls the 16-slot row until all valid, reduces in-wave. Stale values from a
// previous graph replay are bit-identical (deterministic) -> harmless.
// Key: (distbits|msb)<<32 | (0xFFFFFFFF - idx); u64 '>' == (dist desc, idx asc).
// Validity: embedded idx < NPTS (memset-0 row decodes idx=0xFFFFFFFF invalid).
// ---------------------------------------------------------------------------
__global__ __launch_bounds__(256)
void fps_kernel_multi(const float* __restrict__ spatial, int* __restrict__ sidx,
                      unsigned long long* __restrict__ slots)
{
    const int b     = blockIdx.x >> 2;
    const int shard = blockIdx.x & 3;
    const int t     = threadIdx.x;
    const int lane  = t & 63;
    const int wv    = (shard << 2) | (t >> 6);       // 0..15 within batch
    const float* pts = spatial + (size_t)b * NPTS * SDIM;
    unsigned long long* bslots = slots + (size_t)b * NS * 16;

    const int base = wv << 9;                         // wv*512
    float px0[8], px1[8], px2[8], px3[8], px4[8];
    float dist[8];
#pragma unroll
    for (int j = 0; j < 8; ++j) {
        const int i = base + j * 64 + lane;
        px0[j] = pts[i * SDIM + 0];
        px1[j] = pts[i * SDIM + 1];
        px2[j] = pts[i * SDIM + 2];
        px3[j] = pts[i * SDIM + 3];
        px4[j] = pts[i * SDIM + 4];
        dist[j] = __builtin_inff();
    }
    if (wv == 0 && lane == 0) {
        dist[0] = -__builtin_inff();                  // point 0 pre-selected
        sidx[b * NS] = 0;
    }

    int bsel = 0;
    for (int step = 1; step < NS; ++step) {
        const float* qp = pts + bsel * SDIM;          // bsel uniform -> scalar loads
        const float q0 = qp[0], q1 = qp[1], q2 = qp[2], q3 = qp[3], q4 = qp[4];

        float bestv = -__builtin_inff();
        int   besti = 0;
#pragma unroll
        for (int j = 0; j < 8; ++j) {
            float a  = sqdist5(px0[j], px1[j], px2[j], px3[j], px4[j],
                               q0, q1, q2, q3, q4);
            float nd = fminf(dist[j], a);
            dist[j] = nd;
            if (nd > bestv) { bestv = nd; besti = base + j * 64 + lane; }
        }
        // wave argmax (64 lanes), tie-break lower global index
#pragma unroll
        for (int off = 32; off > 0; off >>= 1) {
            float ov = __shfl_xor(bestv, off);
            int   oi = __shfl_xor(besti, off);
            if (ov > bestv || (ov == bestv && oi < besti)) { bestv = ov; besti = oi; }
        }
        const unsigned int kv = (bestv < 0.0f) ? 0u
                                               : (__float_as_uint(bestv) | 0x80000000u);
        const unsigned long long key =
            ((unsigned long long)kv << 32) |
            (unsigned long long)(0xFFFFFFFFu - (unsigned)besti);
        unsigned long long* row = bslots + (size_t)step * 16;
        if (lane == 0)
            __hip_atomic_store(row + wv, key, __ATOMIC_RELAXED, __HIP_MEMORY_SCOPE_AGENT);

        // poll all 16 shard keys (lanes load lane&15 -> one 128B line)
        unsigned long long kk;
        const unsigned long long* pslot = row + (lane & 15);
        for (;;) {
            kk = __hip_atomic_load(pslot, __ATOMIC_RELAXED, __HIP_MEMORY_SCOPE_AGENT);
            const bool valid = (0xFFFFFFFFu - (unsigned int)kk) < NPTS;
            if (__all(valid)) break;
        }
#pragma unroll
        for (int off = 1; off < 16; off <<= 1) {
            const unsigned long long o = __shfl_xor(kk, off);
            if (o > kk) kk = o;
        }
        const int sel = (int)(0xFFFFFFFFu - (unsigned int)(kk & 0xFFFFFFFFull));
        if (wv == 0 && lane == 0) sidx[b * NS + step] = sel;
        bsel = __builtin_amdgcn_readfirstlane(sel);

        const int off_ = bsel - base;
        if (off_ >= 0 && off_ < 512 && (off_ & 63) == lane) {
            const int jj = off_ >> 6;
#pragma unroll
            for (int j = 0; j < 8; ++j)               // static indexing only
                if (j == jj) dist[j] = -__builtin_inff();
        }
    }
}

// ---------------------------------------------------------------------------
// Kernel 1 (v1 fallback, used if ws_size too small): single block per batch.
// ---------------------------------------------------------------------------
__global__ __launch_bounds__(1024)
void fps_kernel(const float* __restrict__ spatial, int* __restrict__ sidx)
{
    const int b = blockIdx.x;
    const int t = threadIdx.x;
    const float* pts = spatial + (size_t)b * NPTS * SDIM;

    float px0[8], px1[8], px2[8], px3[8], px4[8];
    float dist[8];
#pragma unroll
    for (int j = 0; j < 8; ++j) {
        const int i = j * 1024 + t;
        px0[j] = pts[i * SDIM + 0];
        px1[j] = pts[i * SDIM + 1];
        px2[j] = pts[i * SDIM + 2];
        px3[j] = pts[i * SDIM + 3];
        px4[j] = pts[i * SDIM + 4];
        dist[j] = __builtin_inff();
    }
    if (t == 0) dist[0] = -__builtin_inff();

    __shared__ unsigned long long s_wave[16];
    __shared__ int s_sel;

    if (t == 0) sidx[b * NS] = 0;
    int bsel = 0;

    for (int step = 1; step < NS; ++step) {
        const float* qp = pts + bsel * SDIM;
        const float q0 = qp[0], q1 = qp[1], q2 = qp[2], q3 = qp[3], q4 = qp[4];

        float bestv = -__builtin_inff();
        int   besti = 0;
#pragma unroll
        for (int j = 0; j < 8; ++j) {
            float a  = sqdist5(px0[j], px1[j], px2[j], px3[j], px4[j],
                               q0, q1, q2, q3, q4);
            float nd = fminf(dist[j], a);
            dist[j] = nd;
            if (nd > bestv) { bestv = nd; besti = j * 1024 + t; }
        }
#pragma unroll
        for (int off = 32; off > 0; off >>= 1) {
            float ov = __shfl_xor(bestv, off);
            int   oi = __shfl_xor(besti, off);
            if (ov > bestv || (ov == bestv && oi < besti)) { bestv = ov; besti = oi; }
        }
        if ((t & 63) == 0) {
            unsigned int kv = (bestv < 0.0f) ? 0u
                                             : (__float_as_uint(bestv) | 0x80000000u);
            s_wave[t >> 6] = ((unsigned long long)kv << 32) |
                             (unsigned long long)(0xFFFFFFFFu - (unsigned)besti);
        }
        __syncthreads();
        if (t < 64) {
            unsigned long long kk = (t < 16) ? s_wave[t] : 0ull;
#pragma unroll
            for (int off = 8; off > 0; off >>= 1) {
                unsigned long long o = __shfl_xor(kk, off);
                if (o > kk) kk = o;
            }
            if (t == 0) {
                const int sel = (int)(0xFFFFFFFFu - (unsigned int)(kk & 0xFFFFFFFFull));
                s_sel = sel;
                sidx[b * NS + step] = sel;
            }
        }
        __syncthreads();
        bsel = __builtin_amdgcn_readfirstlane(s_sel);
        const int  jj  = bsel >> 10;
        const bool own = (bsel & 1023) == t;
#pragma unroll
        for (int j = 0; j < 8; ++j)
            if (own && j == jj) dist[j] = -__builtin_inff();
    }
}

// ---------------------------------------------------------------------------
// Kernel 2: kNN (K=3) of each sampled point over the full cloud.
// ---------------------------------------------------------------------------
__global__ __launch_bounds__(256)
void knn_kernel(const float* __restrict__ spatial, const int* __restrict__ sidx,
                int* __restrict__ knn)
{
    const int t   = threadIdx.x;
    const int sl  = t >> 3;
    const int r   = t & 7;
    const int spb = NS / 32;
    const int b   = blockIdx.x / spb;
    const int s   = (blockIdx.x % spb) * 32 + sl;
    const int self = sidx[b * NS + s];
    const float* pts = spatial + (size_t)b * NPTS * SDIM;

    const float q0 = pts[self * SDIM + 0], q1 = pts[self * SDIM + 1],
                q2 = pts[self * SDIM + 2], q3 = pts[self * SDIM + 3],
                q4 = pts[self * SDIM + 4];

    unsigned long long k0 = ~0ull, k1 = ~0ull, k2 = ~0ull;
    for (int i = r; i < NPTS; i += 8) {
        float a = sqdist5(pts[i * SDIM + 0], pts[i * SDIM + 1], pts[i * SDIM + 2],
                          pts[i * SDIM + 3], pts[i * SDIM + 4],
                          q0, q1, q2, q3, q4);
        unsigned long long key = ((unsigned long long)__float_as_uint(a) << 32) |
                                 (unsigned long long)(unsigned)i;
        if (i == self) key = ~0ull;
        if (key < k2) {
            if (key < k1) {
                k2 = k1;
                if (key < k0) { k1 = k0; k0 = key; } else k1 = key;
            } else k2 = key;
        }
    }

    __shared__ unsigned long long sk[256][3];
    sk[t][0] = k0; sk[t][1] = k1; sk[t][2] = k2;
    __syncthreads();

    if (r == 0) {
        unsigned long long b0 = ~0ull, b1 = ~0ull, b2 = ~0ull;
        for (int rr = 0; rr < 8; ++rr) {
#pragma unroll
            for (int m = 0; m < 3; ++m) {
                unsigned long long key = sk[(sl << 3) | rr][m];
                if (key < b2) {
                    if (key < b1) {
                        b2 = b1;
                        if (key < b0) { b1 = b0; b0 = key; } else b1 = key;
                    } else b2 = key;
                }
            }
        }
        const int basei = (b * NS + s) * KNN;
        knn[basei + 0] = (int)(b0 & 0xFFFFFFFFull);
        knn[basei + 1] = (int)(b1 & 0xFFFFFFFFull);
        knn[basei + 2] = (int)(b2 & 0xFFFFFFFFull);
    }
}

// ---------------------------------------------------------------------------
// Kernel 3: gather neighbor features -> second output region (f32).
// ---------------------------------------------------------------------------
__global__ __launch_bounds__(256)
void gather_kernel(const float* __restrict__ x, const int* __restrict__ knn,
                   float* __restrict__ out2)
{
    const long long tid = (long long)blockIdx.x * 256 + threadIdx.x;
    const int       f   = (int)(tid & 63);
    const long long row = tid >> 6;
    const int       idx = knn[row];
    const int       b   = (int)(row / (NS * KNN));
    out2[tid] = x[((size_t)b * NPTS + idx) * FEAT + f];
}

// ---------------------------------------------------------------------------
// Kernel 4a: transpose the 7 weight matrices to [in][out].
// ---------------------------------------------------------------------------
__global__ __launch_bounds__(256)
void transpose_w(const float* __restrict__ w0, const float* __restrict__ w1,
                 const float* __restrict__ w2, const float* __restrict__ w3,
                 const float* __restrict__ w4, const float* __restrict__ w5,
                 const float* __restrict__ w6, float* __restrict__ wt)
{
    const float* w;
    switch (blockIdx.x) {
        case 0: w = w0; break; case 1: w = w1; break; case 2: w = w2; break;
        case 3: w = w3; break; case 4: w = w4; break; case 5: w = w5; break;
        default: w = w6; break;
    }
    float* o = wt + blockIdx.x * 4096;
    for (int e = threadIdx.x; e < 4096; e += 256) {
        const int r = e >> 6, c = e & 63;
        o[c * 64 + r] = w[e];
    }
}

// ---------------------------------------------------------------------------
// Kernel 4b: per-point vector attention MLP chain. One wave per sampled point.
// ---------------------------------------------------------------------------
__global__ __launch_bounds__(256)
void attn_kernel(const float* __restrict__ x, const int* __restrict__ sidx,
                 const float* __restrict__ wt,
                 const float* __restrict__ b_in, const float* __restrict__ b_q,
                 const float* __restrict__ b_k, const float* __restrict__ b_v,
                 const float* __restrict__ b_h1, const float* __restrict__ b_h2,
                 const float* __restrict__ b_out,
                 float* __restrict__ out)
{
    const int lane = threadIdx.x & 63;
    const int wid  = (int)((blockIdx.x * 256 + threadIdx.x) >> 6);
    const int b    = wid >> 12;
    const int si   = sidx[wid];
    const float xs = x[((size_t)b * NPTS + si) * FEAT + lane];

    const float* wt_in  = wt;
    const float* wt_q   = wt + 4096;
    const float* wt_k   = wt + 2 * 4096;
    const float* wt_v   = wt + 3 * 4096;
    const float* wt_h1  = wt + 4 * 4096;
    const float* wt_h2  = wt + 5 * 4096;
    const float* wt_out = wt + 6 * 4096;

    float tv = b_in[lane];
#pragma unroll
    for (int i = 0; i < 64; ++i) tv = fmaf(wt_in[i * 64 + lane], __shfl(xs, i), tv);

    float q = b_q[lane], k = b_k[lane], v = b_v[lane];
#pragma unroll
    for (int i = 0; i < 64; ++i) {
        const float ti = __shfl(tv, i);
        q = fmaf(wt_q[i * 64 + lane], ti, q);
        k = fmaf(wt_k[i * 64 + lane], ti, k);
        v = fmaf(wt_v[i * 64 + lane], ti, v);
    }
    const float d = q - k;
    float h = b_h1[lane];
#pragma unroll
    for (int i = 0; i < 64; ++i) h = fmaf(wt_h1[i * 64 + lane], __shfl(d, i), h);
    h = fmaxf(h, 0.0f);
    float h2 = b_h2[lane];
#pragma unroll
    for (int i = 0; i < 64; ++i) h2 = fmaf(wt_h2[i * 64 + lane], __shfl(h, i), h2);

    float m = h2;
#pragma unroll
    for (int off = 32; off > 0; off >>= 1) m = fmaxf(m, __shfl_xor(m, off));
    const float e = expf(h2 - m);
    float sum = e;
#pragma unroll
    for (int off = 32; off > 0; off >>= 1) sum += __shfl_xor(sum, off);
    const float u = (e / sum) * v;

    float o = b_out[lane];
#pragma unroll
    for (int i = 0; i < 64; ++i) o = fmaf(wt_out[i * 64 + lane], __shfl(u, i), o);
    o += xs;

    out[(size_t)wid * FEAT + lane] = o;
}

// ---------------------------------------------------------------------------
extern "C" void kernel_launch(void* const* d_in, const int* in_sizes, int n_in,
                              void* d_out, int out_size, void* d_ws, size_t ws_size,
                              hipStream_t stream)
{
    const float* x       = (const float*)d_in[0];
    const float* spatial = (const float*)d_in[1];
    const float* w_in    = (const float*)d_in[2];
    const float* b_in    = (const float*)d_in[3];
    const float* w_q     = (const float*)d_in[4];
    const float* b_q     = (const float*)d_in[5];
    const float* w_k     = (const float*)d_in[6];
    const float* b_k     = (const float*)d_in[7];
    const float* w_v     = (const float*)d_in[8];
    const float* b_v     = (const float*)d_in[9];
    const float* w_h1    = (const float*)d_in[10];
    const float* b_h1    = (const float*)d_in[11];
    const float* w_h2    = (const float*)d_in[12];
    const float* b_h2    = (const float*)d_in[13];
    const float* w_out   = (const float*)d_in[14];
    const float* b_out   = (const float*)d_in[15];

    int*   sidx = (int*)((char*)d_ws + WS_SIDX_OFF);
    int*   knn  = (int*)((char*)d_ws + WS_KNN_OFF);
    float* wt   = (float*)((char*)d_ws + WS_WT_OFF);

    float* out  = (float*)d_out;
    float* out2 = out + (size_t)NBATCH * NS * FEAT;

    if (ws_size >= WS_NEED) {
        unsigned long long* slots = (unsigned long long*)((char*)d_ws + WS_SLOTS_OFF);
        hipMemsetAsync(slots, 0, WS_SLOTS_BYTES, stream);   // 0 -> invalid keys
        hipLaunchKernelGGL(fps_kernel_multi, dim3(NBATCH * 4), dim3(256), 0, stream,
                           spatial, sidx, slots);
    } else {
        hipLaunchKernelGGL(fps_kernel, dim3(NBATCH), dim3(1024), 0, stream,
                           spatial, sidx);
    }
    hipLaunchKernelGGL(transpose_w, dim3(7), dim3(256), 0, stream,
                       w_in, w_q, w_k, w_v, w_h1, w_h2, w_out, wt);
    hipLaunchKernelGGL(knn_kernel, dim3(NBATCH * NS / 32), dim3(256), 0, stream,
                       spatial, sidx, knn);
    hipLaunchKernelGGL(gather_kernel, dim3(NBATCH * NS * KNN * FEAT / 256), dim3(256),
                       0, stream, x, knn, out2);
    hipLaunchKernelGGL(attn_kernel, dim3(NBATCH * NS * FEAT / 256), dim3(256),
                       0, stream, x, sidx, wt,
                       b_in, b_q, b_k, b_v, b_h1, b_h2, b_out, out);
}

// Round 4
// 7222.708 us; speedup vs baseline: 1.5577x; 1.5577x over previous
//
#include <hip/hip_runtime.h>
#include <hip/hip_bf16.h>

#define NPTS 8192
#define SDIM 5
#define NBATCH 4
#define NS 4096
#define FEAT 64
#define KNN 3

// ws layout
#define WS_SIDX_OFF   0               // 4*4096*4   = 64 KB
#define WS_KNN_OFF    65536           // 4*4096*3*4 = 192 KB
#define WS_WT_OFF     262144          // 7*4096*4   = 112 KB

// Pin a value to a VGPR so the compiler cannot contract mul+add into FMA
// (must match numpy's separate-mul-then-add f32 rounding for argmax/top-k
// index stability).
#define NOFUSE(x) asm volatile("" : "+v"(x))

typedef float v2f __attribute__((ext_vector_type(2)));
#define NOFUSE2(x) asm volatile("" : "+v"(x))

__device__ __forceinline__ float sqdist5(float p0, float p1, float p2, float p3, float p4,
                                         float q0, float q1, float q2, float q3, float q4)
{
    float d0 = p0 - q0, d1 = p1 - q1, d2 = p2 - q2, d3 = p3 - q3, d4 = p4 - q4;
    float m0 = d0 * d0; NOFUSE(m0);
    float m1 = d1 * d1; NOFUSE(m1);
    float m2 = d2 * d2; NOFUSE(m2);
    float m3 = d3 * d3; NOFUSE(m3);
    float m4 = d4 * d4; NOFUSE(m4);
    float a = m0 + m1;  // numpy sum order for n=5: sequential left-assoc
    a = a + m2;
    a = a + m3;
    a = a + m4;
    return a;
}

// ---------------------------------------------------------------------------
// Kernel 1 (v3): single block/batch, 1024 threads, ONE barrier per step.
// - float2 packed distance math (v_pk_*_f32), rounding identical to scalar
//   (per-point left-assoc sum chain, NOFUSE pins each square).
// - Per-wave 6-level u64 butterfly; leaders atomicMax into one LDS slot
//   (4-slot ring; slot (s+2)&3 reset by t0 pre-barrier — race-free since the
//   slot's last readers finished before barrier(s-1)).
// - After the single barrier, all lanes broadcast-read the slot and decode.
// Key: (distbits|msb)<<32 | (0xFFFFFFFF - idx); u64 max == (dist desc, idx asc).
// ---------------------------------------------------------------------------
__global__ __launch_bounds__(1024)
void fps_kernel(const float* __restrict__ spatial, int* __restrict__ sidx)
{
    const int b = blockIdx.x;
    const int t = threadIdx.x;
    const int lane = t & 63;
    const float* pts = spatial + (size_t)b * NPTS * SDIM;

    // pair jp holds points j=2jp (lo) and j=2jp+1 (hi); point index = j*1024+t
    v2f px0[4], px1[4], px2[4], px3[4], px4[4];
    float dist[8];
#pragma unroll
    for (int jp = 0; jp < 4; ++jp) {
        const int ilo = (2 * jp) * 1024 + t;
        const int ihi = (2 * jp + 1) * 1024 + t;
        px0[jp] = (v2f){pts[ilo * SDIM + 0], pts[ihi * SDIM + 0]};
        px1[jp] = (v2f){pts[ilo * SDIM + 1], pts[ihi * SDIM + 1]};
        px2[jp] = (v2f){pts[ilo * SDIM + 2], pts[ihi * SDIM + 2]};
        px3[jp] = (v2f){pts[ilo * SDIM + 3], pts[ihi * SDIM + 3]};
        px4[jp] = (v2f){pts[ilo * SDIM + 4], pts[ihi * SDIM + 4]};
        dist[2 * jp] = __builtin_inff();
        dist[2 * jp + 1] = __builtin_inff();
    }
    if (t == 0) {
        dist[0] = -__builtin_inff();          // point 0 pre-selected
        sidx[b * NS] = 0;
    }

    __shared__ unsigned long long slot[4];
    if (t == 0) { slot[0] = 0; slot[1] = 0; slot[2] = 0; slot[3] = 0; }
    __syncthreads();

    int bsel = 0;
    for (int step = 1; step < NS; ++step) {
        const int p = step & 3;
        if (t == 0) slot[(step + 2) & 3] = 0;          // reset future slot

        const float* qp = pts + bsel * SDIM;           // uniform -> scalar loads
        const float q0 = qp[0], q1 = qp[1], q2 = qp[2], q3 = qp[3], q4 = qp[4];
        const v2f q0v = {q0, q0}, q1v = {q1, q1}, q2v = {q2, q2},
                  q3v = {q3, q3}, q4v = {q4, q4};

        float bestv = -__builtin_inff();
        int   besti = 0;
#pragma unroll
        for (int jp = 0; jp < 4; ++jp) {
            v2f d0 = px0[jp] - q0v;
            v2f d1 = px1[jp] - q1v;
            v2f d2 = px2[jp] - q2v;
            v2f d3 = px3[jp] - q3v;
            v2f d4 = px4[jp] - q4v;
            v2f m0 = d0 * d0; NOFUSE2(m0);
            v2f m1 = d1 * d1; NOFUSE2(m1);
            v2f m2 = d2 * d2; NOFUSE2(m2);
            v2f m3 = d3 * d3; NOFUSE2(m3);
            v2f m4 = d4 * d4; NOFUSE2(m4);
            v2f a = m0 + m1;                            // per-point left-assoc
            a = a + m2;
            a = a + m3;
            a = a + m4;
            // lo half (j = 2jp), then hi half (j = 2jp+1): ascending index scan
            {
                float nd = fminf(dist[2 * jp], a.x);
                dist[2 * jp] = nd;
                if (nd > bestv) { bestv = nd; besti = (2 * jp) * 1024 + t; }
            }
            {
                float nd = fminf(dist[2 * jp + 1], a.y);
                dist[2 * jp + 1] = nd;
                if (nd > bestv) { bestv = nd; besti = (2 * jp + 1) * 1024 + t; }
            }
        }

        // pack u64 key and 6-level wave butterfly max
        const unsigned int kv = (bestv < 0.0f) ? 0u
                                               : (__float_as_uint(bestv) | 0x80000000u);
        unsigned long long key =
            ((unsigned long long)kv << 32) |
            (unsigned long long)(0xFFFFFFFFu - (unsigned)besti);
#pragma unroll
        for (int off = 32; off > 0; off >>= 1) {
            const unsigned long long o = __shfl_xor(key, off);
            if (o > key) key = o;
        }
        if (lane == 0) atomicMax(&slot[p], key);
        __syncthreads();

        const unsigned long long kk = slot[p];          // broadcast read
        const int sel = (int)(0xFFFFFFFFu - (unsigned int)(kk & 0xFFFFFFFFull));
        bsel = __builtin_amdgcn_readfirstlane(sel);
        if (t == 0) sidx[b * NS + step] = sel;

        const int  jj  = bsel >> 10;
        const bool own = (bsel & 1023) == t;
#pragma unroll
        for (int j = 0; j < 8; ++j)                     // static indexing only
            if (own && j == jj) dist[j] = -__builtin_inff();
    }
}

// ---------------------------------------------------------------------------
// Kernel 2: kNN (K=3) of each sampled point over the full cloud.
// ---------------------------------------------------------------------------
__global__ __launch_bounds__(256)
void knn_kernel(const float* __restrict__ spatial, const int* __restrict__ sidx,
                int* __restrict__ knn)
{
    const int t   = threadIdx.x;
    const int sl  = t >> 3;
    const int r   = t & 7;
    const int spb = NS / 32;
    const int b   = blockIdx.x / spb;
    const int s   = (blockIdx.x % spb) * 32 + sl;
    const int self = sidx[b * NS + s];
    const float* pts = spatial + (size_t)b * NPTS * SDIM;

    const float q0 = pts[self * SDIM + 0], q1 = pts[self * SDIM + 1],
                q2 = pts[self * SDIM + 2], q3 = pts[self * SDIM + 3],
                q4 = pts[self * SDIM + 4];

    unsigned long long k0 = ~0ull, k1 = ~0ull, k2 = ~0ull;
    for (int i = r; i < NPTS; i += 8) {
        float a = sqdist5(pts[i * SDIM + 0], pts[i * SDIM + 1], pts[i * SDIM + 2],
                          pts[i * SDIM + 3], pts[i * SDIM + 4],
                          q0, q1, q2, q3, q4);
        unsigned long long key = ((unsigned long long)__float_as_uint(a) << 32) |
                                 (unsigned long long)(unsigned)i;
        if (i == self) key = ~0ull;
        if (key < k2) {
            if (key < k1) {
                k2 = k1;
                if (key < k0) { k1 = k0; k0 = key; } else k1 = key;
            } else k2 = key;
        }
    }

    __shared__ unsigned long long sk[256][3];
    sk[t][0] = k0; sk[t][1] = k1; sk[t][2] = k2;
    __syncthreads();

    if (r == 0) {
        unsigned long long b0 = ~0ull, b1 = ~0ull, b2 = ~0ull;
        for (int rr = 0; rr < 8; ++rr) {
#pragma unroll
            for (int m = 0; m < 3; ++m) {
                unsigned long long key = sk[(sl << 3) | rr][m];
                if (key < b2) {
                    if (key < b1) {
                        b2 = b1;
                        if (key < b0) { b1 = b0; b0 = key; } else b1 = key;
                    } else b2 = key;
                }
            }
        }
        const int basei = (b * NS + s) * KNN;
        knn[basei + 0] = (int)(b0 & 0xFFFFFFFFull);
        knn[basei + 1] = (int)(b1 & 0xFFFFFFFFull);
        knn[basei + 2] = (int)(b2 & 0xFFFFFFFFull);
    }
}

// ---------------------------------------------------------------------------
// Kernel 3: gather neighbor features -> second output region (f32).
// ---------------------------------------------------------------------------
__global__ __launch_bounds__(256)
void gather_kernel(const float* __restrict__ x, const int* __restrict__ knn,
                   float* __restrict__ out2)
{
    const long long tid = (long long)blockIdx.x * 256 + threadIdx.x;
    const int       f   = (int)(tid & 63);
    const long long row = tid >> 6;
    const int       idx = knn[row];
    const int       b   = (int)(row / (NS * KNN));
    out2[tid] = x[((size_t)b * NPTS + idx) * FEAT + f];
}

// ---------------------------------------------------------------------------
// Kernel 4a: transpose the 7 weight matrices to [in][out].
// ---------------------------------------------------------------------------
__global__ __launch_bounds__(256)
void transpose_w(const float* __restrict__ w0, const float* __restrict__ w1,
                 const float* __restrict__ w2, const float* __restrict__ w3,
                 const float* __restrict__ w4, const float* __restrict__ w5,
                 const float* __restrict__ w6, float* __restrict__ wt)
{
    const float* w;
    switch (blockIdx.x) {
        case 0: w = w0; break; case 1: w = w1; break; case 2: w = w2; break;
        case 3: w = w3; break; case 4: w = w4; break; case 5: w = w5; break;
        default: w = w6; break;
    }
    float* o = wt + blockIdx.x * 4096;
    for (int e = threadIdx.x; e < 4096; e += 256) {
        const int r = e >> 6, c = e & 63;
        o[c * 64 + r] = w[e];
    }
}

// ---------------------------------------------------------------------------
// Kernel 4b: per-point vector attention MLP chain. One wave per sampled point.
// ---------------------------------------------------------------------------
__global__ __launch_bounds__(256)
void attn_kernel(const float* __restrict__ x, const int* __restrict__ sidx,
                 const float* __restrict__ wt,
                 const float* __restrict__ b_in, const float* __restrict__ b_q,
                 const float* __restrict__ b_k, const float* __restrict__ b_v,
                 const float* __restrict__ b_h1, const float* __restrict__ b_h2,
                 const float* __restrict__ b_out,
                 float* __restrict__ out)
{
    const int lane = threadIdx.x & 63;
    const int wid  = (int)((blockIdx.x * 256 + threadIdx.x) >> 6);
    const int b    = wid >> 12;
    const int si   = sidx[wid];
    const float xs = x[((size_t)b * NPTS + si) * FEAT + lane];

    const float* wt_in  = wt;
    const float* wt_q   = wt + 4096;
    const float* wt_k   = wt + 2 * 4096;
    const float* wt_v   = wt + 3 * 4096;
    const float* wt_h1  = wt + 4 * 4096;
    const float* wt_h2  = wt + 5 * 4096;
    const float* wt_out = wt + 6 * 4096;

    float tv = b_in[lane];
#pragma unroll
    for (int i = 0; i < 64; ++i) tv = fmaf(wt_in[i * 64 + lane], __shfl(xs, i), tv);

    float q = b_q[lane], k = b_k[lane], v = b_v[lane];
#pragma unroll
    for (int i = 0; i < 64; ++i) {
        const float ti = __shfl(tv, i);
        q = fmaf(wt_q[i * 64 + lane], ti, q);
        k = fmaf(wt_k[i * 64 + lane], ti, k);
        v = fmaf(wt_v[i * 64 + lane], ti, v);
    }
    const float d = q - k;
    float h = b_h1[lane];
#pragma unroll
    for (int i = 0; i < 64; ++i) h = fmaf(wt_h1[i * 64 + lane], __shfl(d, i), h);
    h = fmaxf(h, 0.0f);
    float h2 = b_h2[lane];
#pragma unroll
    for (int i = 0; i < 64; ++i) h2 = fmaf(wt_h2[i * 64 + lane], __shfl(h, i), h2);

    float m = h2;
#pragma unroll
    for (int off = 32; off > 0; off >>= 1) m = fmaxf(m, __shfl_xor(m, off));
    const float e = expf(h2 - m);
    float sum = e;
#pragma unroll
    for (int off = 32; off > 0; off >>= 1) sum += __shfl_xor(sum, off);
    const float u = (e / sum) * v;

    float o = b_out[lane];
#pragma unroll
    for (int i = 0; i < 64; ++i) o = fmaf(wt_out[i * 64 + lane], __shfl(u, i), o);
    o += xs;

    out[(size_t)wid * FEAT + lane] = o;
}

// ---------------------------------------------------------------------------
extern "C" void kernel_launch(void* const* d_in, const int* in_sizes, int n_in,
                              void* d_out, int out_size, void* d_ws, size_t ws_size,
                              hipStream_t stream)
{
    const float* x       = (const float*)d_in[0];
    const float* spatial = (const float*)d_in[1];
    const float* w_in    = (const float*)d_in[2];
    const float* b_in    = (const float*)d_in[3];
    const float* w_q     = (const float*)d_in[4];
    const float* b_q     = (const float*)d_in[5];
    const float* w_k     = (const float*)d_in[6];
    const float* b_k     = (const float*)d_in[7];
    const float* w_v     = (const float*)d_in[8];
    const float* b_v     = (const float*)d_in[9];
    const float* w_h1    = (const float*)d_in[10];
    const float* b_h1    = (const float*)d_in[11];
    const float* w_h2    = (const float*)d_in[12];
    const float* b_h2    = (const float*)d_in[13];
    const float* w_out   = (const float*)d_in[14];
    const float* b_out   = (const float*)d_in[15];

    int*   sidx = (int*)((char*)d_ws + WS_SIDX_OFF);
    int*   knn  = (int*)((char*)d_ws + WS_KNN_OFF);
    float* wt   = (float*)((char*)d_ws + WS_WT_OFF);

    float* out  = (float*)d_out;
    float* out2 = out + (size_t)NBATCH * NS * FEAT;

    hipLaunchKernelGGL(fps_kernel, dim3(NBATCH), dim3(1024), 0, stream,
                       spatial, sidx);
    hipLaunchKernelGGL(transpose_w, dim3(7), dim3(256), 0, stream,
                       w_in, w_q, w_k, w_v, w_h1, w_h2, w_out, wt);
    hipLaunchKernelGGL(knn_kernel, dim3(NBATCH * NS / 32), dim3(256), 0, stream,
                       spatial, sidx, knn);
    hipLaunchKernelGGL(gather_kernel, dim3(NBATCH * NS * KNN * FEAT / 256), dim3(256),
                       0, stream, x, knn, out2);
    hipLaunchKernelGGL(attn_kernel, dim3(NBATCH * NS * FEAT / 256), dim3(256),
                       0, stream, x, sidx, wt,
                       b_in, b_q, b_k, b_v, b_h1, b_h2, b_out, out);
}

// Round 5
// 6573.685 us; speedup vs baseline: 1.7115x; 1.0987x over previous
//
#include <hip/hip_runtime.h>
#include <hip/hip_bf16.h>

#define NPTS 8192
#define SDIM 5
#define NBATCH 4
#define NS 4096
#define FEAT 64
#define KNN 3

// ws layout
#define WS_SIDX_OFF   0               // 4*4096*4   = 64 KB
#define WS_KNN_OFF    65536           // 4*4096*3*4 = 192 KB
#define WS_WT_OFF     262144          // 7*4096*4   = 112 KB

// Pin a value to a VGPR so the compiler cannot contract mul+add into FMA
// (must match numpy's separate-mul-then-add f32 rounding for argmax/top-k
// index stability).
#define NOFUSE(x) asm volatile("" : "+v"(x))

typedef float v2f __attribute__((ext_vector_type(2)));
#define NOFUSE2(x) asm volatile("" : "+v"(x))

__device__ __forceinline__ float sqdist5(float p0, float p1, float p2, float p3, float p4,
                                         float q0, float q1, float q2, float q3, float q4)
{
    float d0 = p0 - q0, d1 = p1 - q1, d2 = p2 - q2, d3 = p3 - q3, d4 = p4 - q4;
    float m0 = d0 * d0; NOFUSE(m0);
    float m1 = d1 * d1; NOFUSE(m1);
    float m2 = d2 * d2; NOFUSE(m2);
    float m3 = d3 * d3; NOFUSE(m3);
    float m4 = d4 * d4; NOFUSE(m4);
    float a = m0 + m1;  // numpy sum order for n=5: sequential left-assoc
    a = a + m2;
    a = a + m3;
    a = a + m4;
    return a;
}

// ---------------------------------------------------------------------------
// Kernel 1 (v4): single block/batch, 512 threads (8 waves), 16 pts/lane.
// Rationale: step cost is VALU-issue-bound; per-wave coordination overhead
// (~100 inst: butterfly, key pack, zap, decode) replicates per wave, so fewer,
// fatter waves cut total issue while distance work per SIMD stays constant.
// One barrier per step; LDS atomicMax slot ring (4 slots) as in v3.
// Key: (distbits|msb)<<32 | (0xFFFFFFFF - idx); u64 max == (dist desc, idx asc).
// ---------------------------------------------------------------------------
__global__ __launch_bounds__(512)
void fps_kernel(const float* __restrict__ spatial, int* __restrict__ sidx)
{
    const int b = blockIdx.x;
    const int t = threadIdx.x;
    const int lane = t & 63;
    const float* pts = spatial + (size_t)b * NPTS * SDIM;

    // pair jp holds points j=2jp (lo) and j=2jp+1 (hi); point index i = j*512+t
    v2f px0[8], px1[8], px2[8], px3[8], px4[8];
    float dist[16];
#pragma unroll
    for (int jp = 0; jp < 8; ++jp) {
        const int ilo = (2 * jp) * 512 + t;
        const int ihi = (2 * jp + 1) * 512 + t;
        px0[jp] = (v2f){pts[ilo * SDIM + 0], pts[ihi * SDIM + 0]};
        px1[jp] = (v2f){pts[ilo * SDIM + 1], pts[ihi * SDIM + 1]};
        px2[jp] = (v2f){pts[ilo * SDIM + 2], pts[ihi * SDIM + 2]};
        px3[jp] = (v2f){pts[ilo * SDIM + 3], pts[ihi * SDIM + 3]};
        px4[jp] = (v2f){pts[ilo * SDIM + 4], pts[ihi * SDIM + 4]};
        dist[2 * jp] = __builtin_inff();
        dist[2 * jp + 1] = __builtin_inff();
    }
    if (t == 0) {
        dist[0] = -__builtin_inff();          // point 0 pre-selected
        sidx[b * NS] = 0;
    }

    __shared__ unsigned long long slot[4];
    if (t == 0) { slot[0] = 0; slot[1] = 0; slot[2] = 0; slot[3] = 0; }
    __syncthreads();

    int bsel = 0;
    for (int step = 1; step < NS; ++step) {
        const int p = step & 3;
        if (t == 0) slot[(step + 2) & 3] = 0;          // reset future slot

        const float* qp = pts + bsel * SDIM;           // uniform -> scalar loads
        const float q0 = qp[0], q1 = qp[1], q2 = qp[2], q3 = qp[3], q4 = qp[4];
        const v2f q0v = {q0, q0}, q1v = {q1, q1}, q2v = {q2, q2},
                  q3v = {q3, q3}, q4v = {q4, q4};

        float bestv = -__builtin_inff();
        int   besti = 0;
#pragma unroll
        for (int jp = 0; jp < 8; ++jp) {
            v2f d0 = px0[jp] - q0v;
            v2f d1 = px1[jp] - q1v;
            v2f d2 = px2[jp] - q2v;
            v2f d3 = px3[jp] - q3v;
            v2f d4 = px4[jp] - q4v;
            v2f m0 = d0 * d0; NOFUSE2(m0);
            v2f m1 = d1 * d1; NOFUSE2(m1);
            v2f m2 = d2 * d2; NOFUSE2(m2);
            v2f m3 = d3 * d3; NOFUSE2(m3);
            v2f m4 = d4 * d4; NOFUSE2(m4);
            v2f a = m0 + m1;                            // per-point left-assoc
            a = a + m2;
            a = a + m3;
            a = a + m4;
            // lo (j = 2jp) then hi (j = 2jp+1): ascending-index scan,
            // strict '>' keeps the lowest index on exact ties
            {
                float nd = fminf(dist[2 * jp], a.x);
                dist[2 * jp] = nd;
                if (nd > bestv) { bestv = nd; besti = (2 * jp) * 512 + t; }
            }
            {
                float nd = fminf(dist[2 * jp + 1], a.y);
                dist[2 * jp + 1] = nd;
                if (nd > bestv) { bestv = nd; besti = (2 * jp + 1) * 512 + t; }
            }
        }

        // pack u64 key and 6-level wave butterfly max
        const unsigned int kv = (bestv < 0.0f) ? 0u
                                               : (__float_as_uint(bestv) | 0x80000000u);
        unsigned long long key =
            ((unsigned long long)kv << 32) |
            (unsigned long long)(0xFFFFFFFFu - (unsigned)besti);
#pragma unroll
        for (int off = 32; off > 0; off >>= 1) {
            const unsigned long long o = __shfl_xor(key, off);
            if (o > key) key = o;
        }
        if (lane == 0) atomicMax(&slot[p], key);
        __syncthreads();

        const unsigned long long kk = slot[p];          // broadcast read
        const int sel = (int)(0xFFFFFFFFu - (unsigned int)(kk & 0xFFFFFFFFull));
        bsel = __builtin_amdgcn_readfirstlane(sel);
        if (t == 0) sidx[b * NS + step] = sel;

        const int  jj  = bsel >> 9;                     // owner's j slot
        const bool own = (bsel & 511) == t;
#pragma unroll
        for (int j = 0; j < 16; ++j)                    // static indexing only
            if (own && j == jj) dist[j] = -__builtin_inff();
    }
}

// ---------------------------------------------------------------------------
// Kernel 2: kNN (K=3) of each sampled point over the full cloud.
// ---------------------------------------------------------------------------
__global__ __launch_bounds__(256)
void knn_kernel(const float* __restrict__ spatial, const int* __restrict__ sidx,
                int* __restrict__ knn)
{
    const int t   = threadIdx.x;
    const int sl  = t >> 3;
    const int r   = t & 7;
    const int spb = NS / 32;
    const int b   = blockIdx.x / spb;
    const int s   = (blockIdx.x % spb) * 32 + sl;
    const int self = sidx[b * NS + s];
    const float* pts = spatial + (size_t)b * NPTS * SDIM;

    const float q0 = pts[self * SDIM + 0], q1 = pts[self * SDIM + 1],
                q2 = pts[self * SDIM + 2], q3 = pts[self * SDIM + 3],
                q4 = pts[self * SDIM + 4];

    unsigned long long k0 = ~0ull, k1 = ~0ull, k2 = ~0ull;
    for (int i = r; i < NPTS; i += 8) {
        float a = sqdist5(pts[i * SDIM + 0], pts[i * SDIM + 1], pts[i * SDIM + 2],
                          pts[i * SDIM + 3], pts[i * SDIM + 4],
                          q0, q1, q2, q3, q4);
        unsigned long long key = ((unsigned long long)__float_as_uint(a) << 32) |
                                 (unsigned long long)(unsigned)i;
        if (i == self) key = ~0ull;
        if (key < k2) {
            if (key < k1) {
                k2 = k1;
                if (key < k0) { k1 = k0; k0 = key; } else k1 = key;
            } else k2 = key;
        }
    }

    __shared__ unsigned long long sk[256][3];
    sk[t][0] = k0; sk[t][1] = k1; sk[t][2] = k2;
    __syncthreads();

    if (r == 0) {
        unsigned long long b0 = ~0ull, b1 = ~0ull, b2 = ~0ull;
        for (int rr = 0; rr < 8; ++rr) {
#pragma unroll
            for (int m = 0; m < 3; ++m) {
                unsigned long long key = sk[(sl << 3) | rr][m];
                if (key < b2) {
                    if (key < b1) {
                        b2 = b1;
                        if (key < b0) { b1 = b0; b0 = key; } else b1 = key;
                    } else b2 = key;
                }
            }
        }
        const int basei = (b * NS + s) * KNN;
        knn[basei + 0] = (int)(b0 & 0xFFFFFFFFull);
        knn[basei + 1] = (int)(b1 & 0xFFFFFFFFull);
        knn[basei + 2] = (int)(b2 & 0xFFFFFFFFull);
    }
}

// ---------------------------------------------------------------------------
// Kernel 3: gather neighbor features -> second output region (f32).
// ---------------------------------------------------------------------------
__global__ __launch_bounds__(256)
void gather_kernel(const float* __restrict__ x, const int* __restrict__ knn,
                   float* __restrict__ out2)
{
    const long long tid = (long long)blockIdx.x * 256 + threadIdx.x;
    const int       f   = (int)(tid & 63);
    const long long row = tid >> 6;
    const int       idx = knn[row];
    const int       b   = (int)(row / (NS * KNN));
    out2[tid] = x[((size_t)b * NPTS + idx) * FEAT + f];
}

// ---------------------------------------------------------------------------
// Kernel 4a: transpose the 7 weight matrices to [in][out].
// ---------------------------------------------------------------------------
__global__ __launch_bounds__(256)
void transpose_w(const float* __restrict__ w0, const float* __restrict__ w1,
                 const float* __restrict__ w2, const float* __restrict__ w3,
                 const float* __restrict__ w4, const float* __restrict__ w5,
                 const float* __restrict__ w6, float* __restrict__ wt)
{
    const float* w;
    switch (blockIdx.x) {
        case 0: w = w0; break; case 1: w = w1; break; case 2: w = w2; break;
        case 3: w = w3; break; case 4: w = w4; break; case 5: w = w5; break;
        default: w = w6; break;
    }
    float* o = wt + blockIdx.x * 4096;
    for (int e = threadIdx.x; e < 4096; e += 256) {
        const int r = e >> 6, c = e & 63;
        o[c * 64 + r] = w[e];
    }
}

// ---------------------------------------------------------------------------
// Kernel 4b: per-point vector attention MLP chain. One wave per sampled point.
// ---------------------------------------------------------------------------
__global__ __launch_bounds__(256)
void attn_kernel(const float* __restrict__ x, const int* __restrict__ sidx,
                 const float* __restrict__ wt,
                 const float* __restrict__ b_in, const float* __restrict__ b_q,
                 const float* __restrict__ b_k, const float* __restrict__ b_v,
                 const float* __restrict__ b_h1, const float* __restrict__ b_h2,
                 const float* __restrict__ b_out,
                 float* __restrict__ out)
{
    const int lane = threadIdx.x & 63;
    const int wid  = (int)((blockIdx.x * 256 + threadIdx.x) >> 6);
    const int b    = wid >> 12;
    const int si   = sidx[wid];
    const float xs = x[((size_t)b * NPTS + si) * FEAT + lane];

    const float* wt_in  = wt;
    const float* wt_q   = wt + 4096;
    const float* wt_k   = wt + 2 * 4096;
    const float* wt_v   = wt + 3 * 4096;
    const float* wt_h1  = wt + 4 * 4096;
    const float* wt_h2  = wt + 5 * 4096;
    const float* wt_out = wt + 6 * 4096;

    float tv = b_in[lane];
#pragma unroll
    for (int i = 0; i < 64; ++i) tv = fmaf(wt_in[i * 64 + lane], __shfl(xs, i), tv);

    float q = b_q[lane], k = b_k[lane], v = b_v[lane];
#pragma unroll
    for (int i = 0; i < 64; ++i) {
        const float ti = __shfl(tv, i);
        q = fmaf(wt_q[i * 64 + lane], ti, q);
        k = fmaf(wt_k[i * 64 + lane], ti, k);
        v = fmaf(wt_v[i * 64 + lane], ti, v);
    }
    const float d = q - k;
    float h = b_h1[lane];
#pragma unroll
    for (int i = 0; i < 64; ++i) h = fmaf(wt_h1[i * 64 + lane], __shfl(d, i), h);
    h = fmaxf(h, 0.0f);
    float h2 = b_h2[lane];
#pragma unroll
    for (int i = 0; i < 64; ++i) h2 = fmaf(wt_h2[i * 64 + lane], __shfl(h, i), h2);

    float m = h2;
#pragma unroll
    for (int off = 32; off > 0; off >>= 1) m = fmaxf(m, __shfl_xor(m, off));
    const float e = expf(h2 - m);
    float sum = e;
#pragma unroll
    for (int off = 32; off > 0; off >>= 1) sum += __shfl_xor(sum, off);
    const float u = (e / sum) * v;

    float o = b_out[lane];
#pragma unroll
    for (int i = 0; i < 64; ++i) o = fmaf(wt_out[i * 64 + lane], __shfl(u, i), o);
    o += xs;

    out[(size_t)wid * FEAT + lane] = o;
}

// ---------------------------------------------------------------------------
extern "C" void kernel_launch(void* const* d_in, const int* in_sizes, int n_in,
                              void* d_out, int out_size, void* d_ws, size_t ws_size,
                              hipStream_t stream)
{
    const float* x       = (const float*)d_in[0];
    const float* spatial = (const float*)d_in[1];
    const float* w_in    = (const float*)d_in[2];
    const float* b_in    = (const float*)d_in[3];
    const float* w_q     = (const float*)d_in[4];
    const float* b_q     = (const float*)d_in[5];
    const float* w_k     = (const float*)d_in[6];
    const float* b_k     = (const float*)d_in[7];
    const float* w_v     = (const float*)d_in[8];
    const float* b_v     = (const float*)d_in[9];
    const float* w_h1    = (const float*)d_in[10];
    const float* b_h1    = (const float*)d_in[11];
    const float* w_h2    = (const float*)d_in[12];
    const float* b_h2    = (const float*)d_in[13];
    const float* w_out   = (const float*)d_in[14];
    const float* b_out   = (const float*)d_in[15];

    int*   sidx = (int*)((char*)d_ws + WS_SIDX_OFF);
    int*   knn  = (int*)((char*)d_ws + WS_KNN_OFF);
    float* wt   = (float*)((char*)d_ws + WS_WT_OFF);

    float* out  = (float*)d_out;
    float* out2 = out + (size_t)NBATCH * NS * FEAT;

    hipLaunchKernelGGL(fps_kernel, dim3(NBATCH), dim3(512), 0, stream,
                       spatial, sidx);
    hipLaunchKernelGGL(transpose_w, dim3(7), dim3(256), 0, stream,
                       w_in, w_q, w_k, w_v, w_h1, w_h2, w_out, wt);
    hipLaunchKernelGGL(knn_kernel, dim3(NBATCH * NS / 32), dim3(256), 0, stream,
                       spatial, sidx, knn);
    hipLaunchKernelGGL(gather_kernel, dim3(NBATCH * NS * KNN * FEAT / 256), dim3(256),
                       0, stream, x, knn, out2);
    hipLaunchKernelGGL(attn_kernel, dim3(NBATCH * NS * FEAT / 256), dim3(256),
                       0, stream, x, sidx, wt,
                       b_in, b_q, b_k, b_v, b_h1, b_h2, b_out, out);
}

// Round 6
// 5720.533 us; speedup vs baseline: 1.9667x; 1.1491x over previous
//
#include <hip/hip_runtime.h>
#include <hip/hip_bf16.h>

#define NPTS 8192
#define SDIM 5
#define NBATCH 4
#define NS 4096
#define FEAT 64
#define KNN 3

// ws layout
#define WS_SIDX_OFF   0               // 4*4096*4   = 64 KB
#define WS_KNN_OFF    65536           // 4*4096*3*4 = 192 KB
#define WS_WT_OFF     262144          // 7*4096*4   = 112 KB

// Pin a value to a VGPR so the compiler cannot contract mul+add into FMA
// (must match numpy's separate-mul-then-add f32 rounding for argmax/top-k
// index stability).
#define NOFUSE(x) asm volatile("" : "+v"(x))

typedef float v2f __attribute__((ext_vector_type(2)));
#define NOFUSE2(x) asm volatile("" : "+v"(x))

__device__ __forceinline__ float sqdist5(float p0, float p1, float p2, float p3, float p4,
                                         float q0, float q1, float q2, float q3, float q4)
{
    float d0 = p0 - q0, d1 = p1 - q1, d2 = p2 - q2, d3 = p3 - q3, d4 = p4 - q4;
    float m0 = d0 * d0; NOFUSE(m0);
    float m1 = d1 * d1; NOFUSE(m1);
    float m2 = d2 * d2; NOFUSE(m2);
    float m3 = d3 * d3; NOFUSE(m3);
    float m4 = d4 * d4; NOFUSE(m4);
    float a = m0 + m1;  // numpy sum order for n=5: sequential left-assoc
    a = a + m2;
    a = a + m3;
    a = a + m4;
    return a;
}

// ---------------------------------------------------------------------------
// VALU-only 64-lane reductions via DPP (row_shr 1/2/4/8 + row_bcast15/31).
// update_dpp(old=identity,...): out-of-range source lanes yield the identity,
// so the max/min is unaffected. Result accumulates in lane 63 -> readlane.
// All VALU, ~4cy/op dependent chain — replaces the 12-deep ds_bpermute chain.
// ---------------------------------------------------------------------------
__device__ __forceinline__ float wave_max_f32_bcast(float v)
{
    int x;
    x = __builtin_amdgcn_update_dpp(0xFF800000, __float_as_int(v), 0x111, 0xf, 0xf, false);
    v = fmaxf(v, __int_as_float(x));   // row_shr:1
    x = __builtin_amdgcn_update_dpp(0xFF800000, __float_as_int(v), 0x112, 0xf, 0xf, false);
    v = fmaxf(v, __int_as_float(x));   // row_shr:2
    x = __builtin_amdgcn_update_dpp(0xFF800000, __float_as_int(v), 0x114, 0xf, 0xf, false);
    v = fmaxf(v, __int_as_float(x));   // row_shr:4
    x = __builtin_amdgcn_update_dpp(0xFF800000, __float_as_int(v), 0x118, 0xf, 0xf, false);
    v = fmaxf(v, __int_as_float(x));   // row_shr:8
    x = __builtin_amdgcn_update_dpp(0xFF800000, __float_as_int(v), 0x142, 0xf, 0xf, false);
    v = fmaxf(v, __int_as_float(x));   // row_bcast:15
    x = __builtin_amdgcn_update_dpp(0xFF800000, __float_as_int(v), 0x143, 0xf, 0xf, false);
    v = fmaxf(v, __int_as_float(x));   // row_bcast:31
    return __int_as_float(__builtin_amdgcn_readlane(__float_as_int(v), 63));
}

__device__ __forceinline__ int wave_min_i32_bcast(int v)
{
    int x;
    x = __builtin_amdgcn_update_dpp(0x7FFFFFFF, v, 0x111, 0xf, 0xf, false);
    v = min(v, x);
    x = __builtin_amdgcn_update_dpp(0x7FFFFFFF, v, 0x112, 0xf, 0xf, false);
    v = min(v, x);
    x = __builtin_amdgcn_update_dpp(0x7FFFFFFF, v, 0x114, 0xf, 0xf, false);
    v = min(v, x);
    x = __builtin_amdgcn_update_dpp(0x7FFFFFFF, v, 0x118, 0xf, 0xf, false);
    v = min(v, x);
    x = __builtin_amdgcn_update_dpp(0x7FFFFFFF, v, 0x142, 0xf, 0xf, false);
    v = min(v, x);
    x = __builtin_amdgcn_update_dpp(0x7FFFFFFF, v, 0x143, 0xf, 0xf, false);
    v = min(v, x);
    return __builtin_amdgcn_readlane(v, 63);
}

// ---------------------------------------------------------------------------
// Kernel 1 (v5): single block/batch, 512 threads (8 waves), 16 pts/lane.
// Per step: packed-f32 dist update (v_pk_*), per-lane argmax scan, DPP wave
// argmax (value then lowest-index), lane0 atomicMax u64 key into LDS slot
// ring, ONE barrier, decode. Selection math bit-identical to v3/v4.
// Key: (distbits|msb)<<32 | (0xFFFFFFFF - idx); u64 max == (dist desc, idx asc).
// ---------------------------------------------------------------------------
__global__ __launch_bounds__(512)
void fps_kernel(const float* __restrict__ spatial, int* __restrict__ sidx)
{
    const int b = blockIdx.x;
    const int t = threadIdx.x;
    const int lane = t & 63;
    const float* pts = spatial + (size_t)b * NPTS * SDIM;

    // pair jp holds points j=2jp (lo=.x) and j=2jp+1 (hi=.y); index i = j*512+t
    v2f px0[8], px1[8], px2[8], px3[8], px4[8];
    v2f dist2[8];
#pragma unroll
    for (int jp = 0; jp < 8; ++jp) {
        const int ilo = (2 * jp) * 512 + t;
        const int ihi = (2 * jp + 1) * 512 + t;
        px0[jp] = (v2f){pts[ilo * SDIM + 0], pts[ihi * SDIM + 0]};
        px1[jp] = (v2f){pts[ilo * SDIM + 1], pts[ihi * SDIM + 1]};
        px2[jp] = (v2f){pts[ilo * SDIM + 2], pts[ihi * SDIM + 2]};
        px3[jp] = (v2f){pts[ilo * SDIM + 3], pts[ihi * SDIM + 3]};
        px4[jp] = (v2f){pts[ilo * SDIM + 4], pts[ihi * SDIM + 4]};
        dist2[jp] = (v2f){__builtin_inff(), __builtin_inff()};
    }
    if (t == 0) {
        dist2[0].x = -__builtin_inff();       // point 0 pre-selected
        sidx[b * NS] = 0;
    }

    __shared__ unsigned long long slot[4];
    if (t == 0) { slot[0] = 0; slot[1] = 0; slot[2] = 0; slot[3] = 0; }
    __syncthreads();

    int bsel = 0;
    for (int step = 1; step < NS; ++step) {
        const int p = step & 3;
        if (t == 0) slot[(step + 2) & 3] = 0;          // reset future slot

        const float* qp = pts + bsel * SDIM;           // uniform -> scalar loads
        const float q0 = qp[0], q1 = qp[1], q2 = qp[2], q3 = qp[3], q4 = qp[4];
        const v2f q0v = {q0, q0}, q1v = {q1, q1}, q2v = {q2, q2},
                  q3v = {q3, q3}, q4v = {q4, q4};

        float bestv = -__builtin_inff();
        int   besti = 0;
#pragma unroll
        for (int jp = 0; jp < 8; ++jp) {
            v2f d0 = px0[jp] - q0v;
            v2f d1 = px1[jp] - q1v;
            v2f d2 = px2[jp] - q2v;
            v2f d3 = px3[jp] - q3v;
            v2f d4 = px4[jp] - q4v;
            v2f m0 = d0 * d0; NOFUSE2(m0);
            v2f m1 = d1 * d1; NOFUSE2(m1);
            v2f m2 = d2 * d2; NOFUSE2(m2);
            v2f m3 = d3 * d3; NOFUSE2(m3);
            v2f m4 = d4 * d4; NOFUSE2(m4);
            v2f a = m0 + m1;                            // per-point left-assoc
            a = a + m2;
            a = a + m3;
            a = a + m4;
            const v2f nd = __builtin_elementwise_min(dist2[jp], a);  // v_pk_min
            dist2[jp] = nd;
            // lo (j=2jp) then hi (j=2jp+1): ascending-index scan, strict '>'
            if (nd.x > bestv) { bestv = nd.x; besti = (2 * jp) * 512 + t; }
            if (nd.y > bestv) { bestv = nd.y; besti = (2 * jp + 1) * 512 + t; }
        }

        // wave argmax: value via DPP max, then lowest index among exact ties
        const float maxv = wave_max_f32_bcast(bestv);
        const int   cand = (bestv == maxv) ? besti : 0x7FFFFFFF;
        const int   mini = wave_min_i32_bcast(cand);

        if (lane == 0) {
            const unsigned int kv = (maxv < 0.0f) ? 0u
                                                  : (__float_as_uint(maxv) | 0x80000000u);
            const unsigned long long key =
                ((unsigned long long)kv << 32) |
                (unsigned long long)(0xFFFFFFFFu - (unsigned)mini);
            atomicMax(&slot[p], key);
        }
        __syncthreads();

        const unsigned long long kk = slot[p];          // broadcast read
        const int sel = (int)(0xFFFFFFFFu - (unsigned int)(kk & 0xFFFFFFFFull));
        bsel = __builtin_amdgcn_readfirstlane(sel);
        if (t == 0) sidx[b * NS + step] = sel;

        const int  jj  = bsel >> 9;                     // owner's j slot
        const bool own = (bsel & 511) == t;
#pragma unroll
        for (int jp = 0; jp < 8; ++jp) {                // static indexing only
            if (own && jj == 2 * jp)     dist2[jp].x = -__builtin_inff();
            if (own && jj == 2 * jp + 1) dist2[jp].y = -__builtin_inff();
        }
    }
}

// ---------------------------------------------------------------------------
// Kernel 2: kNN (K=3) of each sampled point over the full cloud.
// ---------------------------------------------------------------------------
__global__ __launch_bounds__(256)
void knn_kernel(const float* __restrict__ spatial, const int* __restrict__ sidx,
                int* __restrict__ knn)
{
    const int t   = threadIdx.x;
    const int sl  = t >> 3;
    const int r   = t & 7;
    const int spb = NS / 32;
    const int b   = blockIdx.x / spb;
    const int s   = (blockIdx.x % spb) * 32 + sl;
    const int self = sidx[b * NS + s];
    const float* pts = spatial + (size_t)b * NPTS * SDIM;

    const float q0 = pts[self * SDIM + 0], q1 = pts[self * SDIM + 1],
                q2 = pts[self * SDIM + 2], q3 = pts[self * SDIM + 3],
                q4 = pts[self * SDIM + 4];

    unsigned long long k0 = ~0ull, k1 = ~0ull, k2 = ~0ull;
    for (int i = r; i < NPTS; i += 8) {
        float a = sqdist5(pts[i * SDIM + 0], pts[i * SDIM + 1], pts[i * SDIM + 2],
                          pts[i * SDIM + 3], pts[i * SDIM + 4],
                          q0, q1, q2, q3, q4);
        unsigned long long key = ((unsigned long long)__float_as_uint(a) << 32) |
                                 (unsigned long long)(unsigned)i;
        if (i == self) key = ~0ull;
        if (key < k2) {
            if (key < k1) {
                k2 = k1;
                if (key < k0) { k1 = k0; k0 = key; } else k1 = key;
            } else k2 = key;
        }
    }

    __shared__ unsigned long long sk[256][3];
    sk[t][0] = k0; sk[t][1] = k1; sk[t][2] = k2;
    __syncthreads();

    if (r == 0) {
        unsigned long long b0 = ~0ull, b1 = ~0ull, b2 = ~0ull;
        for (int rr = 0; rr < 8; ++rr) {
#pragma unroll
            for (int m = 0; m < 3; ++m) {
                unsigned long long key = sk[(sl << 3) | rr][m];
                if (key < b2) {
                    if (key < b1) {
                        b2 = b1;
                        if (key < b0) { b1 = b0; b0 = key; } else b1 = key;
                    } else b2 = key;
                }
            }
        }
        const int basei = (b * NS + s) * KNN;
        knn[basei + 0] = (int)(b0 & 0xFFFFFFFFull);
        knn[basei + 1] = (int)(b1 & 0xFFFFFFFFull);
        knn[basei + 2] = (int)(b2 & 0xFFFFFFFFull);
    }
}

// ---------------------------------------------------------------------------
// Kernel 3: gather neighbor features -> second output region (f32).
// ---------------------------------------------------------------------------
__global__ __launch_bounds__(256)
void gather_kernel(const float* __restrict__ x, const int* __restrict__ knn,
                   float* __restrict__ out2)
{
    const long long tid = (long long)blockIdx.x * 256 + threadIdx.x;
    const int       f   = (int)(tid & 63);
    const long long row = tid >> 6;
    const int       idx = knn[row];
    const int       b   = (int)(row / (NS * KNN));
    out2[tid] = x[((size_t)b * NPTS + idx) * FEAT + f];
}

// ---------------------------------------------------------------------------
// Kernel 4a: transpose the 7 weight matrices to [in][out].
// ---------------------------------------------------------------------------
__global__ __launch_bounds__(256)
void transpose_w(const float* __restrict__ w0, const float* __restrict__ w1,
                 const float* __restrict__ w2, const float* __restrict__ w3,
                 const float* __restrict__ w4, const float* __restrict__ w5,
                 const float* __restrict__ w6, float* __restrict__ wt)
{
    const float* w;
    switch (blockIdx.x) {
        case 0: w = w0; break; case 1: w = w1; break; case 2: w = w2; break;
        case 3: w = w3; break; case 4: w = w4; break; case 5: w = w5; break;
        default: w = w6; break;
    }
    float* o = wt + blockIdx.x * 4096;
    for (int e = threadIdx.x; e < 4096; e += 256) {
        const int r = e >> 6, c = e & 63;
        o[c * 64 + r] = w[e];
    }
}

// ---------------------------------------------------------------------------
// Kernel 4b: per-point vector attention MLP chain. One wave per sampled point.
// ---------------------------------------------------------------------------
__global__ __launch_bounds__(256)
void attn_kernel(const float* __restrict__ x, const int* __restrict__ sidx,
                 const float* __restrict__ wt,
                 const float* __restrict__ b_in, const float* __restrict__ b_q,
                 const float* __restrict__ b_k, const float* __restrict__ b_v,
                 const float* __restrict__ b_h1, const float* __restrict__ b_h2,
                 const float* __restrict__ b_out,
                 float* __restrict__ out)
{
    const int lane = threadIdx.x & 63;
    const int wid  = (int)((blockIdx.x * 256 + threadIdx.x) >> 6);
    const int b    = wid >> 12;
    const int si   = sidx[wid];
    const float xs = x[((size_t)b * NPTS + si) * FEAT + lane];

    const float* wt_in  = wt;
    const float* wt_q   = wt + 4096;
    const float* wt_k   = wt + 2 * 4096;
    const float* wt_v   = wt + 3 * 4096;
    const float* wt_h1  = wt + 4 * 4096;
    const float* wt_h2  = wt + 5 * 4096;
    const float* wt_out = wt + 6 * 4096;

    float tv = b_in[lane];
#pragma unroll
    for (int i = 0; i < 64; ++i) tv = fmaf(wt_in[i * 64 + lane], __shfl(xs, i), tv);

    float q = b_q[lane], k = b_k[lane], v = b_v[lane];
#pragma unroll
    for (int i = 0; i < 64; ++i) {
        const float ti = __shfl(tv, i);
        q = fmaf(wt_q[i * 64 + lane], ti, q);
        k = fmaf(wt_k[i * 64 + lane], ti, k);
        v = fmaf(wt_v[i * 64 + lane], ti, v);
    }
    const float d = q - k;
    float h = b_h1[lane];
#pragma unroll
    for (int i = 0; i < 64; ++i) h = fmaf(wt_h1[i * 64 + lane], __shfl(d, i), h);
    h = fmaxf(h, 0.0f);
    float h2 = b_h2[lane];
#pragma unroll
    for (int i = 0; i < 64; ++i) h2 = fmaf(wt_h2[i * 64 + lane], __shfl(h, i), h2);

    float m = h2;
#pragma unroll
    for (int off = 32; off > 0; off >>= 1) m = fmaxf(m, __shfl_xor(m, off));
    const float e = expf(h2 - m);
    float sum = e;
#pragma unroll
    for (int off = 32; off > 0; off >>= 1) sum += __shfl_xor(sum, off);
    const float u = (e / sum) * v;

    float o = b_out[lane];
#pragma unroll
    for (int i = 0; i < 64; ++i) o = fmaf(wt_out[i * 64 + lane], __shfl(u, i), o);
    o += xs;

    out[(size_t)wid * FEAT + lane] = o;
}

// ---------------------------------------------------------------------------
extern "C" void kernel_launch(void* const* d_in, const int* in_sizes, int n_in,
                              void* d_out, int out_size, void* d_ws, size_t ws_size,
                              hipStream_t stream)
{
    const float* x       = (const float*)d_in[0];
    const float* spatial = (const float*)d_in[1];
    const float* w_in    = (const float*)d_in[2];
    const float* b_in    = (const float*)d_in[3];
    const float* w_q     = (const float*)d_in[4];
    const float* b_q     = (const float*)d_in[5];
    const float* w_k     = (const float*)d_in[6];
    const float* b_k     = (const float*)d_in[7];
    const float* w_v     = (const float*)d_in[8];
    const float* b_v     = (const float*)d_in[9];
    const float* w_h1    = (const float*)d_in[10];
    const float* b_h1    = (const float*)d_in[11];
    const float* w_h2    = (const float*)d_in[12];
    const float* b_h2    = (const float*)d_in[13];
    const float* w_out   = (const float*)d_in[14];
    const float* b_out   = (const float*)d_in[15];

    int*   sidx = (int*)((char*)d_ws + WS_SIDX_OFF);
    int*   knn  = (int*)((char*)d_ws + WS_KNN_OFF);
    float* wt   = (float*)((char*)d_ws + WS_WT_OFF);

    float* out  = (float*)d_out;
    float* out2 = out + (size_t)NBATCH * NS * FEAT;

    hipLaunchKernelGGL(fps_kernel, dim3(NBATCH), dim3(512), 0, stream,
                       spatial, sidx);
    hipLaunchKernelGGL(transpose_w, dim3(7), dim3(256), 0, stream,
                       w_in, w_q, w_k, w_v, w_h1, w_h2, w_out, wt);
    hipLaunchKernelGGL(knn_kernel, dim3(NBATCH * NS / 32), dim3(256), 0, stream,
                       spatial, sidx, knn);
    hipLaunchKernelGGL(gather_kernel, dim3(NBATCH * NS * KNN * FEAT / 256), dim3(256),
                       0, stream, x, knn, out2);
    hipLaunchKernelGGL(attn_kernel, dim3(NBATCH * NS * FEAT / 256), dim3(256),
                       0, stream, x, sidx, wt,
                       b_in, b_q, b_k, b_v, b_h1, b_h2, b_out, out);
}

// Round 7
// 5586.806 us; speedup vs baseline: 2.0138x; 1.0239x over previous
//
#include <hip/hip_runtime.h>
#include <hip/hip_bf16.h>

#define NPTS 8192
#define SDIM 5
#define NBATCH 4
#define NS 4096
#define FEAT 64
#define KNN 3

// ws layout
#define WS_SIDX_OFF   0               // 4*4096*4   = 64 KB
#define WS_KNN_OFF    65536           // 4*4096*3*4 = 192 KB
#define WS_WT_OFF     262144          // 7*4096*4   = 112 KB

typedef float v2f __attribute__((ext_vector_type(2)));

// NOTE on numerics: numpy computes ((((d0*d0+d1*d1)+d2*d2)+d3*d3)+d4*d4) with
// separate mul and add (no FMA). HIP defaults to -ffp-contract=fast, which
// would fuse and change argmax/top-k tie outcomes. Instead of asm register
// pins (which cost v_movs and block pk-op formation — measured ~2x VALU issue
// inflation in rounds 4-6), we disable contraction per-function with
// `#pragma clang fp contract(off)`. No fast-math is enabled, so ops are never
// reassociated: results are bit-identical to numpy's op order.

__device__ __forceinline__ float sqdist5(float p0, float p1, float p2, float p3, float p4,
                                         float q0, float q1, float q2, float q3, float q4)
{
#pragma clang fp contract(off)
    float d0 = p0 - q0, d1 = p1 - q1, d2 = p2 - q2, d3 = p3 - q3, d4 = p4 - q4;
    float a = d0 * d0 + d1 * d1;
    a = a + d2 * d2;
    a = a + d3 * d3;
    a = a + d4 * d4;
    return a;
}

// ---------------------------------------------------------------------------
// VALU-only 64-lane reductions via DPP (row_shr 1/2/4/8 + row_bcast15/31).
// update_dpp(old=identity,...): out-of-range source lanes yield the identity,
// so the max/min is unaffected. Result accumulates in lane 63 -> readlane.
// ---------------------------------------------------------------------------
__device__ __forceinline__ float wave_max_f32_bcast(float v)
{
    int x;
    x = __builtin_amdgcn_update_dpp(0xFF800000, __float_as_int(v), 0x111, 0xf, 0xf, false);
    v = fmaxf(v, __int_as_float(x));   // row_shr:1
    x = __builtin_amdgcn_update_dpp(0xFF800000, __float_as_int(v), 0x112, 0xf, 0xf, false);
    v = fmaxf(v, __int_as_float(x));   // row_shr:2
    x = __builtin_amdgcn_update_dpp(0xFF800000, __float_as_int(v), 0x114, 0xf, 0xf, false);
    v = fmaxf(v, __int_as_float(x));   // row_shr:4
    x = __builtin_amdgcn_update_dpp(0xFF800000, __float_as_int(v), 0x118, 0xf, 0xf, false);
    v = fmaxf(v, __int_as_float(x));   // row_shr:8
    x = __builtin_amdgcn_update_dpp(0xFF800000, __float_as_int(v), 0x142, 0xf, 0xf, false);
    v = fmaxf(v, __int_as_float(x));   // row_bcast:15
    x = __builtin_amdgcn_update_dpp(0xFF800000, __float_as_int(v), 0x143, 0xf, 0xf, false);
    v = fmaxf(v, __int_as_float(x));   // row_bcast:31
    return __int_as_float(__builtin_amdgcn_readlane(__float_as_int(v), 63));
}

__device__ __forceinline__ int wave_min_i32_bcast(int v)
{
    int x;
    x = __builtin_amdgcn_update_dpp(0x7FFFFFFF, v, 0x111, 0xf, 0xf, false);
    v = min(v, x);
    x = __builtin_amdgcn_update_dpp(0x7FFFFFFF, v, 0x112, 0xf, 0xf, false);
    v = min(v, x);
    x = __builtin_amdgcn_update_dpp(0x7FFFFFFF, v, 0x114, 0xf, 0xf, false);
    v = min(v, x);
    x = __builtin_amdgcn_update_dpp(0x7FFFFFFF, v, 0x118, 0xf, 0xf, false);
    v = min(v, x);
    x = __builtin_amdgcn_update_dpp(0x7FFFFFFF, v, 0x142, 0xf, 0xf, false);
    v = min(v, x);
    x = __builtin_amdgcn_update_dpp(0x7FFFFFFF, v, 0x143, 0xf, 0xf, false);
    v = min(v, x);
    return __builtin_amdgcn_readlane(v, 63);
}

// ---------------------------------------------------------------------------
// Kernel 1 (v6): single block/batch, 512 threads (8 waves), 16 pts/lane.
// Same structure as v5 (packed dist update, DPP wave argmax, LDS atomicMax
// slot ring, one barrier/step) but NO asm pins: contraction disabled by
// pragma, freeing the scheduler and killing the mov overhead.
// Key: (distbits|msb)<<32 | (0xFFFFFFFF - idx); u64 max == (dist desc, idx asc).
// ---------------------------------------------------------------------------
__global__ __launch_bounds__(512)
void fps_kernel(const float* __restrict__ spatial, int* __restrict__ sidx)
{
#pragma clang fp contract(off)
    const int b = blockIdx.x;
    const int t = threadIdx.x;
    const int lane = t & 63;
    const float* pts = spatial + (size_t)b * NPTS * SDIM;

    // pair jp holds points j=2jp (lo=.x) and j=2jp+1 (hi=.y); index i = j*512+t
    v2f px0[8], px1[8], px2[8], px3[8], px4[8];
    v2f dist2[8];
#pragma unroll
    for (int jp = 0; jp < 8; ++jp) {
        const int ilo = (2 * jp) * 512 + t;
        const int ihi = (2 * jp + 1) * 512 + t;
        px0[jp] = (v2f){pts[ilo * SDIM + 0], pts[ihi * SDIM + 0]};
        px1[jp] = (v2f){pts[ilo * SDIM + 1], pts[ihi * SDIM + 1]};
        px2[jp] = (v2f){pts[ilo * SDIM + 2], pts[ihi * SDIM + 2]};
        px3[jp] = (v2f){pts[ilo * SDIM + 3], pts[ihi * SDIM + 3]};
        px4[jp] = (v2f){pts[ilo * SDIM + 4], pts[ihi * SDIM + 4]};
        dist2[jp] = (v2f){__builtin_inff(), __builtin_inff()};
    }
    if (t == 0) {
        dist2[0].x = -__builtin_inff();       // point 0 pre-selected
        sidx[b * NS] = 0;
    }

    __shared__ unsigned long long slot[4];
    if (t == 0) { slot[0] = 0; slot[1] = 0; slot[2] = 0; slot[3] = 0; }
    __syncthreads();

    int bsel = 0;
    for (int step = 1; step < NS; ++step) {
        const int p = step & 3;
        if (t == 0) slot[(step + 2) & 3] = 0;          // reset future slot

        const float* qp = pts + bsel * SDIM;           // uniform -> scalar loads
        const float q0 = qp[0], q1 = qp[1], q2 = qp[2], q3 = qp[3], q4 = qp[4];
        const v2f q0v = {q0, q0}, q1v = {q1, q1}, q2v = {q2, q2},
                  q3v = {q3, q3}, q4v = {q4, q4};

        float bestv = -__builtin_inff();
        int   besti = 0;
#pragma unroll
        for (int jp = 0; jp < 8; ++jp) {
            v2f d0 = px0[jp] - q0v;
            v2f d1 = px1[jp] - q1v;
            v2f d2 = px2[jp] - q2v;
            v2f d3 = px3[jp] - q3v;
            v2f d4 = px4[jp] - q4v;
            v2f a = d0 * d0 + d1 * d1;                  // per-point left-assoc
            a = a + d2 * d2;
            a = a + d3 * d3;
            a = a + d4 * d4;
            const v2f nd = __builtin_elementwise_min(dist2[jp], a);
            dist2[jp] = nd;
            // lo (j=2jp) then hi (j=2jp+1): ascending-index scan, strict '>'
            if (nd.x > bestv) { bestv = nd.x; besti = (2 * jp) * 512 + t; }
            if (nd.y > bestv) { bestv = nd.y; besti = (2 * jp + 1) * 512 + t; }
        }

        // wave argmax: value via DPP max, then lowest index among exact ties
        const float maxv = wave_max_f32_bcast(bestv);
        const int   cand = (bestv == maxv) ? besti : 0x7FFFFFFF;
        const int   mini = wave_min_i32_bcast(cand);

        if (lane == 0) {
            const unsigned int kv = (maxv < 0.0f) ? 0u
                                                  : (__float_as_uint(maxv) | 0x80000000u);
            const unsigned long long key =
                ((unsigned long long)kv << 32) |
                (unsigned long long)(0xFFFFFFFFu - (unsigned)mini);
            atomicMax(&slot[p], key);
        }
        __syncthreads();

        const unsigned long long kk = slot[p];          // broadcast read
        const int sel = (int)(0xFFFFFFFFu - (unsigned int)(kk & 0xFFFFFFFFull));
        bsel = __builtin_amdgcn_readfirstlane(sel);
        if (t == 0) sidx[b * NS + step] = sel;

        const int  jj  = bsel >> 9;                     // owner's j slot
        const bool own = (bsel & 511) == t;
#pragma unroll
        for (int jp = 0; jp < 8; ++jp) {                // static indexing only
            if (own && jj == 2 * jp)     dist2[jp].x = -__builtin_inff();
            if (own && jj == 2 * jp + 1) dist2[jp].y = -__builtin_inff();
        }
    }
}

// ---------------------------------------------------------------------------
// Kernel 2: kNN (K=3) of each sampled point over the full cloud.
// ---------------------------------------------------------------------------
__global__ __launch_bounds__(256)
void knn_kernel(const float* __restrict__ spatial, const int* __restrict__ sidx,
                int* __restrict__ knn)
{
    const int t   = threadIdx.x;
    const int sl  = t >> 3;
    const int r   = t & 7;
    const int spb = NS / 32;
    const int b   = blockIdx.x / spb;
    const int s   = (blockIdx.x % spb) * 32 + sl;
    const int self = sidx[b * NS + s];
    const float* pts = spatial + (size_t)b * NPTS * SDIM;

    const float q0 = pts[self * SDIM + 0], q1 = pts[self * SDIM + 1],
                q2 = pts[self * SDIM + 2], q3 = pts[self * SDIM + 3],
                q4 = pts[self * SDIM + 4];

    unsigned long long k0 = ~0ull, k1 = ~0ull, k2 = ~0ull;
    for (int i = r; i < NPTS; i += 8) {
        float a = sqdist5(pts[i * SDIM + 0], pts[i * SDIM + 1], pts[i * SDIM + 2],
                          pts[i * SDIM + 3], pts[i * SDIM + 4],
                          q0, q1, q2, q3, q4);
        unsigned long long key = ((unsigned long long)__float_as_uint(a) << 32) |
                                 (unsigned long long)(unsigned)i;
        if (i == self) key = ~0ull;
        if (key < k2) {
            if (key < k1) {
                k2 = k1;
                if (key < k0) { k1 = k0; k0 = key; } else k1 = key;
            } else k2 = key;
        }
    }

    __shared__ unsigned long long sk[256][3];
    sk[t][0] = k0; sk[t][1] = k1; sk[t][2] = k2;
    __syncthreads();

    if (r == 0) {
        unsigned long long b0 = ~0ull, b1 = ~0ull, b2 = ~0ull;
        for (int rr = 0; rr < 8; ++rr) {
#pragma unroll
            for (int m = 0; m < 3; ++m) {
                unsigned long long key = sk[(sl << 3) | rr][m];
                if (key < b2) {
                    if (key < b1) {
                        b2 = b1;
                        if (key < b0) { b1 = b0; b0 = key; } else b1 = key;
                    } else b2 = key;
                }
            }
        }
        const int basei = (b * NS + s) * KNN;
        knn[basei + 0] = (int)(b0 & 0xFFFFFFFFull);
        knn[basei + 1] = (int)(b1 & 0xFFFFFFFFull);
        knn[basei + 2] = (int)(b2 & 0xFFFFFFFFull);
    }
}

// ---------------------------------------------------------------------------
// Kernel 3: gather neighbor features -> second output region (f32).
// ---------------------------------------------------------------------------
__global__ __launch_bounds__(256)
void gather_kernel(const float* __restrict__ x, const int* __restrict__ knn,
                   float* __restrict__ out2)
{
    const long long tid = (long long)blockIdx.x * 256 + threadIdx.x;
    const int       f   = (int)(tid & 63);
    const long long row = tid >> 6;
    const int       idx = knn[row];
    const int       b   = (int)(row / (NS * KNN));
    out2[tid] = x[((size_t)b * NPTS + idx) * FEAT + f];
}

// ---------------------------------------------------------------------------
// Kernel 4a: transpose the 7 weight matrices to [in][out].
// ---------------------------------------------------------------------------
__global__ __launch_bounds__(256)
void transpose_w(const float* __restrict__ w0, const float* __restrict__ w1,
                 const float* __restrict__ w2, const float* __restrict__ w3,
                 const float* __restrict__ w4, const float* __restrict__ w5,
                 const float* __restrict__ w6, float* __restrict__ wt)
{
    const float* w;
    switch (blockIdx.x) {
        case 0: w = w0; break; case 1: w = w1; break; case 2: w = w2; break;
        case 3: w = w3; break; case 4: w = w4; break; case 5: w = w5; break;
        default: w = w6; break;
    }
    float* o = wt + blockIdx.x * 4096;
    for (int e = threadIdx.x; e < 4096; e += 256) {
        const int r = e >> 6, c = e & 63;
        o[c * 64 + r] = w[e];
    }
}

// ---------------------------------------------------------------------------
// Kernel 4b: per-point vector attention MLP chain. One wave per sampled point.
// ---------------------------------------------------------------------------
__global__ __launch_bounds__(256)
void attn_kernel(const float* __restrict__ x, const int* __restrict__ sidx,
                 const float* __restrict__ wt,
                 const float* __restrict__ b_in, const float* __restrict__ b_q,
                 const float* __restrict__ b_k, const float* __restrict__ b_v,
                 const float* __restrict__ b_h1, const float* __restrict__ b_h2,
                 const float* __restrict__ b_out,
                 float* __restrict__ out)
{
    const int lane = threadIdx.x & 63;
    const int wid  = (int)((blockIdx.x * 256 + threadIdx.x) >> 6);
    const int b    = wid >> 12;
    const int si   = sidx[wid];
    const float xs = x[((size_t)b * NPTS + si) * FEAT + lane];

    const float* wt_in  = wt;
    const float* wt_q   = wt + 4096;
    const float* wt_k   = wt + 2 * 4096;
    const float* wt_v   = wt + 3 * 4096;
    const float* wt_h1  = wt + 4 * 4096;
    const float* wt_h2  = wt + 5 * 4096;
    const float* wt_out = wt + 6 * 4096;

    float tv = b_in[lane];
#pragma unroll
    for (int i = 0; i < 64; ++i) tv = fmaf(wt_in[i * 64 + lane], __shfl(xs, i), tv);

    float q = b_q[lane], k = b_k[lane], v = b_v[lane];
#pragma unroll
    for (int i = 0; i < 64; ++i) {
        const float ti = __shfl(tv, i);
        q = fmaf(wt_q[i * 64 + lane], ti, q);
        k = fmaf(wt_k[i * 64 + lane], ti, k);
        v = fmaf(wt_v[i * 64 + lane], ti, v);
    }
    const float d = q - k;
    float h = b_h1[lane];
#pragma unroll
    for (int i = 0; i < 64; ++i) h = fmaf(wt_h1[i * 64 + lane], __shfl(d, i), h);
    h = fmaxf(h, 0.0f);
    float h2 = b_h2[lane];
#pragma unroll
    for (int i = 0; i < 64; ++i) h2 = fmaf(wt_h2[i * 64 + lane], __shfl(h, i), h2);

    float m = h2;
#pragma unroll
    for (int off = 32; off > 0; off >>= 1) m = fmaxf(m, __shfl_xor(m, off));
    const float e = expf(h2 - m);
    float sum = e;
#pragma unroll
    for (int off = 32; off > 0; off >>= 1) sum += __shfl_xor(sum, off);
    const float u = (e / sum) * v;

    float o = b_out[lane];
#pragma unroll
    for (int i = 0; i < 64; ++i) o = fmaf(wt_out[i * 64 + lane], __shfl(u, i), o);
    o += xs;

    out[(size_t)wid * FEAT + lane] = o;
}

// ---------------------------------------------------------------------------
extern "C" void kernel_launch(void* const* d_in, const int* in_sizes, int n_in,
                              void* d_out, int out_size, void* d_ws, size_t ws_size,
                              hipStream_t stream)
{
    const float* x       = (const float*)d_in[0];
    const float* spatial = (const float*)d_in[1];
    const float* w_in    = (const float*)d_in[2];
    const float* b_in    = (const float*)d_in[3];
    const float* w_q     = (const float*)d_in[4];
    const float* b_q     = (const float*)d_in[5];
    const float* w_k     = (const float*)d_in[6];
    const float* b_k     = (const float*)d_in[7];
    const float* w_v     = (const float*)d_in[8];
    const float* b_v     = (const float*)d_in[9];
    const float* w_h1    = (const float*)d_in[10];
    const float* b_h1    = (const float*)d_in[11];
    const float* w_h2    = (const float*)d_in[12];
    const float* b_h2    = (const float*)d_in[13];
    const float* w_out   = (const float*)d_in[14];
    const float* b_out   = (const float*)d_in[15];

    int*   sidx = (int*)((char*)d_ws + WS_SIDX_OFF);
    int*   knn  = (int*)((char*)d_ws + WS_KNN_OFF);
    float* wt   = (float*)((char*)d_ws + WS_WT_OFF);

    float* out  = (float*)d_out;
    float* out2 = out + (size_t)NBATCH * NS * FEAT;

    hipLaunchKernelGGL(fps_kernel, dim3(NBATCH), dim3(512), 0, stream,
                       spatial, sidx);
    hipLaunchKernelGGL(transpose_w, dim3(7), dim3(256), 0, stream,
                       w_in, w_q, w_k, w_v, w_h1, w_h2, w_out, wt);
    hipLaunchKernelGGL(knn_kernel, dim3(NBATCH * NS / 32), dim3(256), 0, stream,
                       spatial, sidx, knn);
    hipLaunchKernelGGL(gather_kernel, dim3(NBATCH * NS * KNN * FEAT / 256), dim3(256),
                       0, stream, x, knn, out2);
    hipLaunchKernelGGL(attn_kernel, dim3(NBATCH * NS * FEAT / 256), dim3(256),
                       0, stream, x, sidx, wt,
                       b_in, b_q, b_k, b_v, b_h1, b_h2, b_out, out);
}